// Round 9
// baseline (1239.387 us; speedup 1.0000x reference)
//
#include <hip/hip_runtime.h>
#include <hip/hip_bf16.h>

#define NNUE_INPUTS 41024
#define L1N 128
#define L2N 32
#define L3N 32
#define MAX_ACT 512
#define NC_ROW (NNUE_INPUTS / 4)     // 10256 float4 chunks per row
#define NC_HALF (NC_ROW / 2)         // 5128 chunks per half-row (per wave)
#define WITER 20                     // 20*256 = 5120 chunks; tail = 8 per wave

typedef float f4 __attribute__((ext_vector_type(4)));

__device__ __forceinline__ float clip01(float x) {
    return fminf(fmaxf(x, 0.0f), 1.0f);
}

// R7 verified structure (absmax 0.0), with ONLY the occupancy bound changed:
// (256,4) -> (256,8) to allow 8 blocks/CU = 32 waves/CU on the dense-stream scan.
__global__ __launch_bounds__(256, 8) void nnue_fused_kernel(
    const float* __restrict__ us, const float* __restrict__ them,
    const float* __restrict__ w_in, const float* __restrict__ b_in,
    const float* __restrict__ W_ft, const float* __restrict__ b_ft,
    const float* __restrict__ W1, const float* __restrict__ b1,
    const float* __restrict__ W2, const float* __restrict__ b2,
    const float* __restrict__ Wo, const float* __restrict__ bo,
    float* __restrict__ out)
{
    __shared__ int   s_idx_w[MAX_ACT];
    __shared__ int   s_idx_b[MAX_ACT];
    __shared__ int   s_cnt[2];
    __shared__ float s_w[L1N];
    __shared__ float s_b[L1N];
    __shared__ float s_l0[2 * L1N];
    __shared__ float s_part[8][L2N];
    __shared__ float s_l1[L2N];
    __shared__ float s_l2[L3N];

    const int row  = blockIdx.x;
    const int tid  = threadIdx.x;
    const int wave = tid >> 6;          // 0..3
    const int lane = tid & 63;

    if (tid < 2) s_cnt[tid] = 0;
    const float u = us[row];
    const float t = them[row];
    __syncthreads();

    // ---- Phase 1: ONE dense contiguous stream per wave ----
    // waves 0,1 -> w-row halves 0,1 ; waves 2,3 -> b-row halves 0,1.
    {
        const int     p    = wave >> 1;                     // 0 = w, 1 = b
        const f4*     src  = (const f4*)((p ? b_in : w_in) + (size_t)row * NNUE_INPUTS);
        int*          mcnt = &s_cnt[p];
        int*          midx = p ? s_idx_b : s_idx_w;
        const int     base = (wave & 1) * NC_HALF;          // chunk offset of this wave's half

        auto emit = [&](const f4& x, int c) {               // c = chunk index in row
            const int e = c * 4;
            if (x[0] != 0.0f) { int q = atomicAdd(mcnt, 1); midx[q & (MAX_ACT - 1)] = e;     }
            if (x[1] != 0.0f) { int q = atomicAdd(mcnt, 1); midx[q & (MAX_ACT - 1)] = e + 1; }
            if (x[2] != 0.0f) { int q = atomicAdd(mcnt, 1); midx[q & (MAX_ACT - 1)] = e + 2; }
            if (x[3] != 0.0f) { int q = atomicAdd(mcnt, 1); midx[q & (MAX_ACT - 1)] = e + 3; }
        };
        auto proc4 = [&](int c0, const f4& x0, const f4& x1, const f4& x2, const f4& x3) {
            const float s = (((x0[0] + x0[1]) + (x0[2] + x0[3])) + ((x1[0] + x1[1]) + (x1[2] + x1[3])))
                          + (((x2[0] + x2[1]) + (x2[2] + x2[3])) + ((x3[0] + x3[1]) + (x3[2] + x3[3])));
            if (__any(s != 0.0f)) {
                emit(x0, c0);
                emit(x1, c0 + 64);
                emit(x2, c0 + 128);
                emit(x3, c0 + 192);
            }
        };

        // distance-1 pipelined: wave-iter i covers chunks [base+i*256, base+(i+1)*256)
        int c = base + lane;
        f4 x0 = src[c], x1 = src[c + 64], x2 = src[c + 128], x3 = src[c + 192];
        #pragma unroll 1
        for (int i = 0; i < WITER - 1; ++i) {
            const int cn = c + 256;
            const f4 n0 = src[cn], n1 = src[cn + 64], n2 = src[cn + 128], n3 = src[cn + 192];
            proc4(c, x0, x1, x2, x3);
            x0 = n0; x1 = n1; x2 = n2; x3 = n3;
            c = cn;
        }
        proc4(c, x0, x1, x2, x3);
        // tail: last 8 chunks of this wave's half on lanes 0..7
        if (lane < NC_HALF - WITER * 256) {
            const int ct = base + WITER * 256 + lane;
            const f4 x = src[ct];
            const float s = (x[0] + x[1]) + (x[2] + x[3]);
            if (__any(s != 0.0f)) { if (s != 0.0f) emit(x, ct); }
        }
    }
    __syncthreads();

    const int kw = min(s_cnt[0], MAX_ACT);
    const int kb = min(s_cnt[1], MAX_ACT);

    // ---- Phase 2: gather W_ft rows ----
    {
        const int  ch   = tid & (L1N - 1);
        const bool is_b = tid >= L1N;
        const int* lst  = is_b ? s_idx_b : s_idx_w;
        const int  K    = is_b ? kb : kw;
        const float* Wc = W_ft + ch;
        float acc = b_ft[ch];
        int k = 0;
        for (; k + 4 <= K; k += 4) {
            const int i0 = lst[k], i1 = lst[k + 1], i2 = lst[k + 2], i3 = lst[k + 3];
            const float f0 = Wc[(size_t)i0 * L1N];
            const float f1 = Wc[(size_t)i1 * L1N];
            const float f2 = Wc[(size_t)i2 * L1N];
            const float f3 = Wc[(size_t)i3 * L1N];
            acc += f0; acc += f1; acc += f2; acc += f3;
        }
        for (; k < K; ++k) acc += Wc[(size_t)lst[k] * L1N];
        if (is_b) s_b[ch] = acc; else s_w[ch] = acc;
    }
    __syncthreads();

    // ---- Phase 3: perspective mix + clip -> l0 [256] ----
    if (tid < L1N) {
        const float wv = s_w[tid], bv = s_b[tid];
        s_l0[tid]       = clip01(u * wv + t * bv);
        s_l0[L1N + tid] = clip01(u * bv + t * wv);
    }
    __syncthreads();

    // ---- l1 = clip(l0 @ W1 + b1): 8 chunks x 32 outputs ----
    {
        const int o  = tid & 31;
        const int ch = tid >> 5;
        float a = 0.0f;
        const int k0 = ch * 32;
        #pragma unroll
        for (int k = 0; k < 32; ++k) a += s_l0[k0 + k] * W1[(k0 + k) * L2N + o];
        s_part[ch][o] = a;
    }
    __syncthreads();
    if (tid < L2N) {
        float a = b1[tid];
        #pragma unroll
        for (int j = 0; j < 8; ++j) a += s_part[j][tid];
        s_l1[tid] = clip01(a);
    }
    __syncthreads();

    // ---- l2 = clip(l1 @ W2 + b2) ----
    if (tid < L3N) {
        float a = b2[tid];
        #pragma unroll
        for (int k = 0; k < L2N; ++k) a += s_l1[k] * W2[k * L3N + tid];
        s_l2[tid] = clip01(a);
    }
    __syncthreads();

    // ---- out = l2 @ Wo + bo ----
    if (tid == 0) {
        float a = bo[0];
        #pragma unroll
        for (int k = 0; k < L3N; ++k) a += s_l2[k] * Wo[k];
        out[row] = a;
    }
}

extern "C" void kernel_launch(void* const* d_in, const int* in_sizes, int n_in,
                              void* d_out, int out_size, void* d_ws, size_t ws_size,
                              hipStream_t stream) {
    const float* us   = (const float*)d_in[0];
    const float* them = (const float*)d_in[1];
    const float* w_in = (const float*)d_in[2];
    const float* b_in = (const float*)d_in[3];
    const float* W_ft = (const float*)d_in[4];
    const float* b_ft = (const float*)d_in[5];
    const float* W1   = (const float*)d_in[6];
    const float* b1   = (const float*)d_in[7];
    const float* W2   = (const float*)d_in[8];
    const float* b2   = (const float*)d_in[9];
    const float* Wo   = (const float*)d_in[10];
    const float* bo   = (const float*)d_in[11];
    float* out = (float*)d_out;

    const int B = in_sizes[0];  // 4096
    nnue_fused_kernel<<<dim3(B), dim3(256), 0, stream>>>(
        us, them, w_in, b_in, W_ft, b_ft, W1, b1, W2, b2, Wo, bo, out);
}

// Round 10
// 1234.010 us; speedup vs baseline: 1.0044x; 1.0044x over previous
//
#include <hip/hip_runtime.h>
#include <hip/hip_bf16.h>

#define NNUE_INPUTS 41024
#define L1N 128
#define L2N 32
#define L3N 32
#define MAX_ACT 512
#define NC_ROW (NNUE_INPUTS / 4)     // 10256 float4 chunks per row
#define NC_HALF (NC_ROW / 2)         // 5128 chunks per half-row (per wave)
#define WITER 20                     // 20*256 = 5120 chunks; tail = 8 per wave

typedef float f4 __attribute__((ext_vector_type(4)));

__device__ __forceinline__ float clip01(float x) {
    return fminf(fmaxf(x, 0.0f), 1.0f);
}

// Final kernel: R7 verified structure (absmax 0.0, 1220 us — session best).
// One dense contiguous 82KB stream per wave; (256,4) bound keeps the pipelined
// scan + unrolled gather spill-free (the (256,8) variant regressed: 64-VGPR cap).
__global__ __launch_bounds__(256, 4) void nnue_fused_kernel(
    const float* __restrict__ us, const float* __restrict__ them,
    const float* __restrict__ w_in, const float* __restrict__ b_in,
    const float* __restrict__ W_ft, const float* __restrict__ b_ft,
    const float* __restrict__ W1, const float* __restrict__ b1,
    const float* __restrict__ W2, const float* __restrict__ b2,
    const float* __restrict__ Wo, const float* __restrict__ bo,
    float* __restrict__ out)
{
    __shared__ int   s_idx_w[MAX_ACT];
    __shared__ int   s_idx_b[MAX_ACT];
    __shared__ int   s_cnt[2];
    __shared__ float s_w[L1N];
    __shared__ float s_b[L1N];
    __shared__ float s_l0[2 * L1N];
    __shared__ float s_part[8][L2N];
    __shared__ float s_l1[L2N];
    __shared__ float s_l2[L3N];

    const int row  = blockIdx.x;
    const int tid  = threadIdx.x;
    const int wave = tid >> 6;          // 0..3
    const int lane = tid & 63;

    if (tid < 2) s_cnt[tid] = 0;
    const float u = us[row];
    const float t = them[row];
    __syncthreads();

    // ---- Phase 1: ONE dense contiguous stream per wave ----
    // waves 0,1 -> w-row halves 0,1 ; waves 2,3 -> b-row halves 0,1.
    {
        const int     p    = wave >> 1;                     // 0 = w, 1 = b
        const f4*     src  = (const f4*)((p ? b_in : w_in) + (size_t)row * NNUE_INPUTS);
        int*          mcnt = &s_cnt[p];
        int*          midx = p ? s_idx_b : s_idx_w;
        const int     base = (wave & 1) * NC_HALF;          // chunk offset of this wave's half

        auto emit = [&](const f4& x, int c) {               // c = chunk index in row
            const int e = c * 4;
            if (x[0] != 0.0f) { int q = atomicAdd(mcnt, 1); midx[q & (MAX_ACT - 1)] = e;     }
            if (x[1] != 0.0f) { int q = atomicAdd(mcnt, 1); midx[q & (MAX_ACT - 1)] = e + 1; }
            if (x[2] != 0.0f) { int q = atomicAdd(mcnt, 1); midx[q & (MAX_ACT - 1)] = e + 2; }
            if (x[3] != 0.0f) { int q = atomicAdd(mcnt, 1); midx[q & (MAX_ACT - 1)] = e + 3; }
        };
        auto proc4 = [&](int c0, const f4& x0, const f4& x1, const f4& x2, const f4& x3) {
            const float s = (((x0[0] + x0[1]) + (x0[2] + x0[3])) + ((x1[0] + x1[1]) + (x1[2] + x1[3])))
                          + (((x2[0] + x2[1]) + (x2[2] + x2[3])) + ((x3[0] + x3[1]) + (x3[2] + x3[3])));
            if (__any(s != 0.0f)) {
                emit(x0, c0);
                emit(x1, c0 + 64);
                emit(x2, c0 + 128);
                emit(x3, c0 + 192);
            }
        };

        // distance-1 pipelined: wave-iter i covers chunks [base+i*256, base+(i+1)*256)
        int c = base + lane;
        f4 x0 = src[c], x1 = src[c + 64], x2 = src[c + 128], x3 = src[c + 192];
        #pragma unroll 1
        for (int i = 0; i < WITER - 1; ++i) {
            const int cn = c + 256;
            const f4 n0 = src[cn], n1 = src[cn + 64], n2 = src[cn + 128], n3 = src[cn + 192];
            proc4(c, x0, x1, x2, x3);
            x0 = n0; x1 = n1; x2 = n2; x3 = n3;
            c = cn;
        }
        proc4(c, x0, x1, x2, x3);
        // tail: last 8 chunks of this wave's half on lanes 0..7
        if (lane < NC_HALF - WITER * 256) {
            const int ct = base + WITER * 256 + lane;
            const f4 x = src[ct];
            const float s = (x[0] + x[1]) + (x[2] + x[3]);
            if (__any(s != 0.0f)) { if (s != 0.0f) emit(x, ct); }
        }
    }
    __syncthreads();

    const int kw = min(s_cnt[0], MAX_ACT);
    const int kb = min(s_cnt[1], MAX_ACT);

    // ---- Phase 2: gather W_ft rows ----
    {
        const int  ch   = tid & (L1N - 1);
        const bool is_b = tid >= L1N;
        const int* lst  = is_b ? s_idx_b : s_idx_w;
        const int  K    = is_b ? kb : kw;
        const float* Wc = W_ft + ch;
        float acc = b_ft[ch];
        int k = 0;
        for (; k + 4 <= K; k += 4) {
            const int i0 = lst[k], i1 = lst[k + 1], i2 = lst[k + 2], i3 = lst[k + 3];
            const float f0 = Wc[(size_t)i0 * L1N];
            const float f1 = Wc[(size_t)i1 * L1N];
            const float f2 = Wc[(size_t)i2 * L1N];
            const float f3 = Wc[(size_t)i3 * L1N];
            acc += f0; acc += f1; acc += f2; acc += f3;
        }
        for (; k < K; ++k) acc += Wc[(size_t)lst[k] * L1N];
        if (is_b) s_b[ch] = acc; else s_w[ch] = acc;
    }
    __syncthreads();

    // ---- Phase 3: perspective mix + clip -> l0 [256] ----
    if (tid < L1N) {
        const float wv = s_w[tid], bv = s_b[tid];
        s_l0[tid]       = clip01(u * wv + t * bv);
        s_l0[L1N + tid] = clip01(u * bv + t * wv);
    }
    __syncthreads();

    // ---- l1 = clip(l0 @ W1 + b1): 8 chunks x 32 outputs ----
    {
        const int o  = tid & 31;
        const int ch = tid >> 5;
        float a = 0.0f;
        const int k0 = ch * 32;
        #pragma unroll
        for (int k = 0; k < 32; ++k) a += s_l0[k0 + k] * W1[(k0 + k) * L2N + o];
        s_part[ch][o] = a;
    }
    __syncthreads();
    if (tid < L2N) {
        float a = b1[tid];
        #pragma unroll
        for (int j = 0; j < 8; ++j) a += s_part[j][tid];
        s_l1[tid] = clip01(a);
    }
    __syncthreads();

    // ---- l2 = clip(l1 @ W2 + b2) ----
    if (tid < L3N) {
        float a = b2[tid];
        #pragma unroll
        for (int k = 0; k < L2N; ++k) a += s_l1[k] * W2[k * L3N + tid];
        s_l2[tid] = clip01(a);
    }
    __syncthreads();

    // ---- out = l2 @ Wo + bo ----
    if (tid == 0) {
        float a = bo[0];
        #pragma unroll
        for (int k = 0; k < L3N; ++k) a += s_l2[k] * Wo[k];
        out[row] = a;
    }
}

extern "C" void kernel_launch(void* const* d_in, const int* in_sizes, int n_in,
                              void* d_out, int out_size, void* d_ws, size_t ws_size,
                              hipStream_t stream) {
    const float* us   = (const float*)d_in[0];
    const float* them = (const float*)d_in[1];
    const float* w_in = (const float*)d_in[2];
    const float* b_in = (const float*)d_in[3];
    const float* W_ft = (const float*)d_in[4];
    const float* b_ft = (const float*)d_in[5];
    const float* W1   = (const float*)d_in[6];
    const float* b1   = (const float*)d_in[7];
    const float* W2   = (const float*)d_in[8];
    const float* b2   = (const float*)d_in[9];
    const float* Wo   = (const float*)d_in[10];
    const float* bo   = (const float*)d_in[11];
    float* out = (float*)d_out;

    const int B = in_sizes[0];  // 4096
    nnue_fused_kernel<<<dim3(B), dim3(256), 0, stream>>>(
        us, them, w_in, b_in, W_ft, b_ft, W1, b1, W2, b2, Wo, bo, out);
}